// Round 1
// baseline (430.251 us; speedup 1.0000x reference)
//
#include <hip/hip_runtime.h>
#include <hip/hip_bf16.h>

#define Bz 4
#define Sz 2048
#define Dz 1024
#define Hz 16
#define DHz 64
#define Mz (Bz*Sz)      // 8192
#define N3z (3*Dz)      // 3072
#define Kz Dz           // 1024

typedef short s16x8 __attribute__((ext_vector_type(8)));
typedef float f32x4 __attribute__((ext_vector_type(4)));
typedef unsigned short u16;

__device__ __forceinline__ u16 f2b(float f) {
  union { float f; unsigned u; } v; v.f = f;
  unsigned r = v.u + 0x7FFFu + ((v.u >> 16) & 1u);
  return (u16)(r >> 16);
}

// ---------------- x (f32) -> bf16, linear ----------------
__global__ __launch_bounds__(256) void cvt_x(const float* __restrict__ x,
                                             u16* __restrict__ xb) {
  int i = (blockIdx.x * 256 + threadIdx.x) * 4;
  float4 v = *reinterpret_cast<const float4*>(x + i);
  ushort4 o;
  o.x = f2b(v.x); o.y = f2b(v.y); o.z = f2b(v.z); o.w = f2b(v.w);
  *reinterpret_cast<ushort4*>(xb + i) = o;
}

// ---------------- W [K][3D] f32 -> Wt [3D][K] bf16 ----------------
__global__ __launch_bounds__(256) void transpose_w(const float* __restrict__ W,
                                                   u16* __restrict__ Wt) {
  __shared__ u16 t[32][33];
  int nb = blockIdx.x;   // 3072/32 = 96
  int kb = blockIdx.y;   // 1024/32 = 32
  int tx = threadIdx.x, ty = threadIdx.y;
#pragma unroll
  for (int j = 0; j < 4; ++j) {
    int k = kb * 32 + ty + j * 8;
    t[ty + j * 8][tx] = f2b(W[(size_t)k * N3z + nb * 32 + tx]);
  }
  __syncthreads();
#pragma unroll
  for (int j = 0; j < 4; ++j) {
    int n = nb * 32 + ty + j * 8;
    Wt[(size_t)n * Kz + kb * 32 + tx] = t[tx][ty + j * 8];
  }
}

// ---------------- QKV GEMM: [8192,1024] x [1024,3072] + bias ----------------
// m97-structure: 128x128 tile, BK=32, 4 waves (2x2), global_load_lds width 16.
// Epilogue: bias add, Q-scale 1/8, scatter to Q/K/V [B][H][S][DH] bf16.
#define BM 128
#define BN 128
#define BKs 32

__global__ __launch_bounds__(256) void qkv_gemm(
    const u16* __restrict__ A, const u16* __restrict__ Bt,
    const float* __restrict__ bias,
    u16* __restrict__ Qo, u16* __restrict__ Ko, u16* __restrict__ Vo) {
  __shared__ alignas(16) u16 As[BM * BKs];  // 8 KB, linear (global_load_lds)
  __shared__ alignas(16) u16 Bs[BN * BKs];  // 8 KB
  const int tid = threadIdx.x;
  const int wid = tid >> 6, lane = tid & 63;
  const int wr = wid >> 1, wc = wid & 1;
  const int g = lane >> 4, lq = lane & 15;
  const int brow = blockIdx.x * BM;
  const int bcol = blockIdx.y * BN;

  f32x4 acc[4][4] = {};

  for (int kt = 0; kt < Kz; kt += BKs) {
    // stage: each wave issues 2 A-chunks + 2 B-chunks of 1024B (16 rows each)
#pragma unroll
    for (int c = 0; c < 2; ++c) {
      int row = (wid * 2 + c) * 16 + (lane >> 2);
      int off = (lane & 3) * 8;
      const u16* ga = A + (size_t)(brow + row) * Kz + kt + off;
      __builtin_amdgcn_global_load_lds(
          (const __attribute__((address_space(1))) void*)ga,
          (__attribute__((address_space(3))) void*)&As[(wid * 2 + c) * 512],
          16, 0, 0);
      const u16* gb = Bt + (size_t)(bcol + row) * Kz + kt + off;
      __builtin_amdgcn_global_load_lds(
          (const __attribute__((address_space(1))) void*)gb,
          (__attribute__((address_space(3))) void*)&Bs[(wid * 2 + c) * 512],
          16, 0, 0);
    }
    __syncthreads();

    s16x8 af[4], bfr[4];
#pragma unroll
    for (int i = 0; i < 4; ++i) {
      af[i]  = *reinterpret_cast<const s16x8*>(&As[(wr * 64 + i * 16 + lq) * BKs + g * 8]);
      bfr[i] = *reinterpret_cast<const s16x8*>(&Bs[(wc * 64 + i * 16 + lq) * BKs + g * 8]);
    }
#pragma unroll
    for (int mi = 0; mi < 4; ++mi)
#pragma unroll
      for (int ni = 0; ni < 4; ++ni)
        acc[mi][ni] = __builtin_amdgcn_mfma_f32_16x16x32_bf16(af[mi], bfr[ni], acc[mi][ni], 0, 0, 0);
    __syncthreads();
  }

  // epilogue: bias + interleave split -> Q/K/V [B][H][S][DH] bf16 (Q pre-scaled)
#pragma unroll
  for (int ni = 0; ni < 4; ++ni) {
    int gcol = bcol + wc * 64 + ni * 16 + lq;     // uniform t/h per fragment column run
    int h = gcol / 192;
    int rem = gcol - h * 192;
    int tt = rem >> 6;
    int dh = rem & 63;
    float bv = bias[gcol];
    u16* dst = (tt == 0) ? Qo : (tt == 1) ? Ko : Vo;
    float scale = (tt == 0) ? 0.125f : 1.0f;
#pragma unroll
    for (int mi = 0; mi < 4; ++mi) {
#pragma unroll
      for (int r = 0; r < 4; ++r) {
        int grow = brow + wr * 64 + mi * 16 + g * 4 + r;
        int bb = grow >> 11;
        int ss = grow & 2047;
        float v = (acc[mi][ni][r] + bv) * scale;
        dst[(((size_t)bb * Hz + h) * Sz + ss) * DHz + dh] = f2b(v);
      }
    }
  }
}

// ---------------- causal flash attention ----------------
// grid (32 qblocks, 64 bh). 256 thr = 4 waves; wave owns 16 q-rows.
// KV tile = 64. K_lds [key][dh+pad]; V_lds transposed [dh][key+pad];
// P via per-wave padded LDS. Online softmax wave-parallel (xor 1,2,4,8).
#define KT 64
#define KSTR 72   // 64 + 8 pad (2-way conflicts only)
#define VSTR 72
#define PSTR 72

__global__ __launch_bounds__(256) void attn_kernel(
    const u16* __restrict__ Qg, const u16* __restrict__ Kg,
    const u16* __restrict__ Vg, float* __restrict__ out) {
  __shared__ alignas(16) u16 Ks[KT * KSTR];       // 9216 B
  __shared__ alignas(16) u16 Vs[DHz * VSTR];      // 9216 B
  __shared__ alignas(16) u16 Ps[4][16 * PSTR];    // 9216 B

  const int qb = blockIdx.x;
  const int bh = blockIdx.y;
  const int tid = threadIdx.x;
  const int wid = tid >> 6, lane = tid & 63;
  const int g = lane >> 4, lq = lane & 15;

  const size_t base = (size_t)bh * Sz * DHz;
  const int q0w = qb * 64 + wid * 16;

  // Q fragments (Q pre-scaled by 1/8 in GEMM epilogue)
  s16x8 qf0 = *reinterpret_cast<const s16x8*>(Qg + base + (size_t)(q0w + lq) * DHz + g * 8);
  s16x8 qf1 = *reinterpret_cast<const s16x8*>(Qg + base + (size_t)(q0w + lq) * DHz + g * 8 + 32);

  f32x4 o[4] = {};
  float m[4] = {-1e30f, -1e30f, -1e30f, -1e30f};
  float l[4] = {0.f, 0.f, 0.f, 0.f};

  const int nt = qb + 1;
  for (int t = 0; t < nt; ++t) {
    const int kv0 = t * 64;
    // ---- stage K (row-major) and V (transposed) ----
#pragma unroll
    for (int c = 0; c < 2; ++c) {
      int chunk = tid + c * 256;
      int row = chunk >> 3;
      int off = (chunk & 7) * 8;
      *reinterpret_cast<s16x8*>(&Ks[row * KSTR + off]) =
          *reinterpret_cast<const s16x8*>(Kg + base + (size_t)(kv0 + row) * DHz + off);
      int vrow = chunk & 63;
      int voff = (chunk >> 6) * 8;
      s16x8 vv = *reinterpret_cast<const s16x8*>(Vg + base + (size_t)(kv0 + vrow) * DHz + voff);
#pragma unroll
      for (int j = 0; j < 8; ++j)
        Vs[(voff + j) * VSTR + vrow] = (u16)vv[j];
    }
    __syncthreads();

    // ---- QK^T ----
    f32x4 sc[4];
#pragma unroll
    for (int f = 0; f < 4; ++f) {
      s16x8 kb0 = *reinterpret_cast<const s16x8*>(&Ks[(f * 16 + lq) * KSTR + g * 8]);
      s16x8 kb1 = *reinterpret_cast<const s16x8*>(&Ks[(f * 16 + lq) * KSTR + g * 8 + 32]);
      f32x4 z = {0.f, 0.f, 0.f, 0.f};
      z = __builtin_amdgcn_mfma_f32_16x16x32_bf16(qf0, kb0, z, 0, 0, 0);
      z = __builtin_amdgcn_mfma_f32_16x16x32_bf16(qf1, kb1, z, 0, 0, 0);
      sc[f] = z;
    }

    if (t == nt - 1) {  // diagonal tile only
#pragma unroll
      for (int f = 0; f < 4; ++f)
#pragma unroll
        for (int r = 0; r < 4; ++r) {
          int key = kv0 + f * 16 + lq;
          int q = q0w + g * 4 + r;
          if (key > q) sc[f][r] = -1e30f;
        }
    }

    // ---- online softmax (rows live on 16-lane groups) ----
    float alpha[4];
#pragma unroll
    for (int r = 0; r < 4; ++r) {
      float v = fmaxf(fmaxf(sc[0][r], sc[1][r]), fmaxf(sc[2][r], sc[3][r]));
      v = fmaxf(v, __shfl_xor(v, 1));
      v = fmaxf(v, __shfl_xor(v, 2));
      v = fmaxf(v, __shfl_xor(v, 4));
      v = fmaxf(v, __shfl_xor(v, 8));
      float mn = fmaxf(m[r], v);
      alpha[r] = __expf(m[r] - mn);
      m[r] = mn;
    }
#pragma unroll
    for (int f = 0; f < 4; ++f)
#pragma unroll
      for (int r = 0; r < 4; ++r)
        sc[f][r] = __expf(sc[f][r] - m[r]);
#pragma unroll
    for (int r = 0; r < 4; ++r) {
      float s = sc[0][r] + sc[1][r] + sc[2][r] + sc[3][r];
      s += __shfl_xor(s, 1);
      s += __shfl_xor(s, 2);
      s += __shfl_xor(s, 4);
      s += __shfl_xor(s, 8);
      l[r] = l[r] * alpha[r] + s;
      o[0][r] *= alpha[r]; o[1][r] *= alpha[r];
      o[2][r] *= alpha[r]; o[3][r] *= alpha[r];
    }

    // ---- P -> per-wave LDS (layout turn), then PV ----
#pragma unroll
    for (int f = 0; f < 4; ++f)
#pragma unroll
      for (int r = 0; r < 4; ++r)
        Ps[wid][(g * 4 + r) * PSTR + f * 16 + lq] = f2b(sc[f][r]);

    s16x8 pa0 = *reinterpret_cast<const s16x8*>(&Ps[wid][lq * PSTR + g * 8]);
    s16x8 pa1 = *reinterpret_cast<const s16x8*>(&Ps[wid][lq * PSTR + g * 8 + 32]);
#pragma unroll
    for (int ni = 0; ni < 4; ++ni) {
      s16x8 vb0 = *reinterpret_cast<const s16x8*>(&Vs[(ni * 16 + lq) * VSTR + g * 8]);
      s16x8 vb1 = *reinterpret_cast<const s16x8*>(&Vs[(ni * 16 + lq) * VSTR + g * 8 + 32]);
      o[ni] = __builtin_amdgcn_mfma_f32_16x16x32_bf16(pa0, vb0, o[ni], 0, 0, 0);
      o[ni] = __builtin_amdgcn_mfma_f32_16x16x32_bf16(pa1, vb1, o[ni], 0, 0, 0);
    }
    __syncthreads();
  }

  // ---- write out [B][S][H][DH] f32 ----
  const int b = bh >> 4, h = bh & 15;
#pragma unroll
  for (int r = 0; r < 4; ++r) {
    float inv = 1.0f / l[r];
    int s = q0w + g * 4 + r;
    float* op = out + (((size_t)b * Sz + s) * Hz + h) * DHz;
#pragma unroll
    for (int ni = 0; ni < 4; ++ni)
      op[ni * 16 + lq] = o[ni][r] * inv;
  }
}

extern "C" void kernel_launch(void* const* d_in, const int* in_sizes, int n_in,
                              void* d_out, int out_size, void* d_ws, size_t ws_size,
                              hipStream_t stream) {
  const float* x    = (const float*)d_in[0];
  const float* W    = (const float*)d_in[1];
  const float* bias = (const float*)d_in[2];
  float* out = (float*)d_out;

  char* ws = (char*)d_ws;
  u16* xb = (u16*)(ws);                      // 16 MB
  u16* wt = (u16*)(ws + 16777216);           // 6 MB
  u16* Qb = (u16*)(ws + 23068672);           // 16 MB
  u16* Kb = (u16*)(ws + 39845888);           // 16 MB
  u16* Vb = (u16*)(ws + 56623104);           // 16 MB  (total ~70 MB)

  cvt_x<<<8192, 256, 0, stream>>>(x, xb);
  transpose_w<<<dim3(96, 32), dim3(32, 8), 0, stream>>>(W, wt);
  qkv_gemm<<<dim3(Mz / BM, N3z / BN), 256, 0, stream>>>(xb, wt, bias, Qb, Kb, Vb);
  attn_kernel<<<dim3(Sz / 64, Bz * Hz), 256, 0, stream>>>(Qb, Kb, Vb, out);
}

// Round 2
// 262.159 us; speedup vs baseline: 1.6412x; 1.6412x over previous
//
#include <hip/hip_runtime.h>
#include <hip/hip_bf16.h>

#define Bz 4
#define Sz 2048
#define Dz 1024
#define Hz 16
#define DHz 64
#define Mz (Bz*Sz)      // 8192
#define N3z (3*Dz)      // 3072
#define Kz Dz           // 1024

typedef short s16x8 __attribute__((ext_vector_type(8)));
typedef float f32x4 __attribute__((ext_vector_type(4)));
typedef unsigned short u16;

__device__ __forceinline__ u16 f2b(float f) {
  union { float f; unsigned u; } v; v.f = f;
  unsigned r = v.u + 0x7FFFu + ((v.u >> 16) & 1u);
  return (u16)(r >> 16);
}

// ---------------- x (f32) -> bf16, linear ----------------
__global__ __launch_bounds__(256) void cvt_x(const float* __restrict__ x,
                                             u16* __restrict__ xb) {
  int i = (blockIdx.x * 256 + threadIdx.x) * 4;
  float4 v = *reinterpret_cast<const float4*>(x + i);
  ushort4 o;
  o.x = f2b(v.x); o.y = f2b(v.y); o.z = f2b(v.z); o.w = f2b(v.w);
  *reinterpret_cast<ushort4*>(xb + i) = o;
}

// ---------------- W [K][3D] f32 -> Wt [3D][K] bf16 ----------------
__global__ __launch_bounds__(256) void transpose_w(const float* __restrict__ W,
                                                   u16* __restrict__ Wt) {
  __shared__ u16 t[32][33];
  int nb = blockIdx.x;   // 3072/32 = 96
  int kb = blockIdx.y;   // 1024/32 = 32
  int tx = threadIdx.x, ty = threadIdx.y;
#pragma unroll
  for (int j = 0; j < 4; ++j) {
    int k = kb * 32 + ty + j * 8;
    t[ty + j * 8][tx] = f2b(W[(size_t)k * N3z + nb * 32 + tx]);
  }
  __syncthreads();
#pragma unroll
  for (int j = 0; j < 4; ++j) {
    int n = nb * 32 + ty + j * 8;
    Wt[(size_t)n * Kz + kb * 32 + tx] = t[tx][ty + j * 8];
  }
}

// ---------------- QKV GEMM: [8192,1024] x [1024,3072] + bias ----------------
#define BM 128
#define BN 128
#define BKs 32

__global__ __launch_bounds__(256) void qkv_gemm(
    const u16* __restrict__ A, const u16* __restrict__ Bt,
    const float* __restrict__ bias,
    u16* __restrict__ Qo, u16* __restrict__ Ko, u16* __restrict__ Vo) {
  __shared__ alignas(16) u16 As[BM * BKs];  // 8 KB, linear (global_load_lds)
  __shared__ alignas(16) u16 Bs[BN * BKs];  // 8 KB
  const int tid = threadIdx.x;
  const int wid = tid >> 6, lane = tid & 63;
  const int wr = wid >> 1, wc = wid & 1;
  const int g = lane >> 4, lq = lane & 15;
  const int brow = blockIdx.x * BM;
  const int bcol = blockIdx.y * BN;

  f32x4 acc[4][4] = {};

  for (int kt = 0; kt < Kz; kt += BKs) {
#pragma unroll
    for (int c = 0; c < 2; ++c) {
      int row = (wid * 2 + c) * 16 + (lane >> 2);
      int off = (lane & 3) * 8;
      const u16* ga = A + (size_t)(brow + row) * Kz + kt + off;
      __builtin_amdgcn_global_load_lds(
          (const __attribute__((address_space(1))) void*)ga,
          (__attribute__((address_space(3))) void*)&As[(wid * 2 + c) * 512],
          16, 0, 0);
      const u16* gb = Bt + (size_t)(bcol + row) * Kz + kt + off;
      __builtin_amdgcn_global_load_lds(
          (const __attribute__((address_space(1))) void*)gb,
          (__attribute__((address_space(3))) void*)&Bs[(wid * 2 + c) * 512],
          16, 0, 0);
    }
    __syncthreads();

    s16x8 af[4], bfr[4];
#pragma unroll
    for (int i = 0; i < 4; ++i) {
      af[i]  = *reinterpret_cast<const s16x8*>(&As[(wr * 64 + i * 16 + lq) * BKs + g * 8]);
      bfr[i] = *reinterpret_cast<const s16x8*>(&Bs[(wc * 64 + i * 16 + lq) * BKs + g * 8]);
    }
#pragma unroll
    for (int mi = 0; mi < 4; ++mi)
#pragma unroll
      for (int ni = 0; ni < 4; ++ni)
        acc[mi][ni] = __builtin_amdgcn_mfma_f32_16x16x32_bf16(af[mi], bfr[ni], acc[mi][ni], 0, 0, 0);
    __syncthreads();
  }

#pragma unroll
  for (int ni = 0; ni < 4; ++ni) {
    int gcol = bcol + wc * 64 + ni * 16 + lq;
    int h = gcol / 192;
    int rem = gcol - h * 192;
    int tt = rem >> 6;
    int dh = rem & 63;
    float bv = bias[gcol];
    u16* dst = (tt == 0) ? Qo : (tt == 1) ? Ko : Vo;
    float scale = (tt == 0) ? 0.125f : 1.0f;
#pragma unroll
    for (int mi = 0; mi < 4; ++mi) {
#pragma unroll
      for (int r = 0; r < 4; ++r) {
        int grow = brow + wr * 64 + mi * 16 + g * 4 + r;
        int bb = grow >> 11;
        int ss = grow & 2047;
        float v = (acc[mi][ni][r] + bv) * scale;
        dst[(((size_t)bb * Hz + h) * Sz + ss) * DHz + dh] = f2b(v);
      }
    }
  }
}

// ---------------- causal flash attention, balanced + swizzled ----------------
// grid (8 qpairs, 64 bh), 512 thr = 8 waves. Block does q-tile qp AND 15-qp
// (128 rows each) -> uniform 34 K-tiles per block (perfect causal balance).
// Wave owns 16 q-rows. KV tile = 64. K and V^T in LDS linear [64][64] with
// XOR swizzle byte^=((row&7)<<4) on BOTH write and read (T2; reg-staged).
// P layout-turn via per-wave padded LDS. Online softmax via 16-lane shfl_xor.
#define PSTR 72

__global__ __launch_bounds__(512, 4) void attn_kernel(
    const u16* __restrict__ Qg, const u16* __restrict__ Kg,
    const u16* __restrict__ Vg, float* __restrict__ out) {
  __shared__ alignas(16) u16 Ks[64 * 64];         // 8192 B, swizzled
  __shared__ alignas(16) u16 Vs[64 * 64];         // 8192 B, V^T [dh][key], swizzled
  __shared__ alignas(16) u16 Ps[8][16 * PSTR];    // 18432 B

  const int qpair = blockIdx.x;   // 0..7
  const int bh = blockIdx.y;      // 0..63
  const int tid = threadIdx.x;
  const int wid = tid >> 6, lane = tid & 63;
  const int g = lane >> 4, lq = lane & 15;
  const size_t base = (size_t)bh * Sz * DHz;
  const int b = bh >> 4, h = bh & 15;

  // staging geometry (512 threads)
  const int krow = tid >> 3;                 // 0..63 (key row)
  const int kslot = tid & 7;                 // 16B slot within 128B row
  const int kswz = kslot ^ (krow & 7);       // swizzled slot
  const int vkey = tid & 63;                 // key (consecutive lanes -> conflict-free writes)
  const int vdh0 = (tid >> 6) * 8;           // dh block

  char* KsB = (char*)Ks;
  char* VsB = (char*)Vs;

  for (int half = 0; half < 2; ++half) {
    const int qt = half ? (15 - qpair) : qpair;       // both halves together cover 0..15
    const int q0w = qt * 128 + wid * 16;

    s16x8 qf0 = *reinterpret_cast<const s16x8*>(Qg + base + (size_t)(q0w + lq) * DHz + g * 8);
    s16x8 qf1 = *reinterpret_cast<const s16x8*>(Qg + base + (size_t)(q0w + lq) * DHz + g * 8 + 32);

    f32x4 o[4] = {};
    float m[4] = {-1e30f, -1e30f, -1e30f, -1e30f};
    float l[4] = {0.f, 0.f, 0.f, 0.f};

    const int nt = 2 * qt + 2;
    for (int t = 0; t < nt; ++t) {
      const int kv0 = t * 64;

      // ---- stage K [key][dh] swizzled (one b128 per thread) ----
      s16x8 kvv = *reinterpret_cast<const s16x8*>(Kg + base + (size_t)(kv0 + krow) * DHz + kslot * 8);
      *reinterpret_cast<s16x8*>(KsB + krow * 128 + kswz * 16) = kvv;
      // ---- stage V^T [dh][key] swizzled (8 scalar writes, consecutive-key lanes) ----
      s16x8 vvv = *reinterpret_cast<const s16x8*>(Vg + base + (size_t)(kv0 + vkey) * DHz + vdh0);
#pragma unroll
      for (int j = 0; j < 8; ++j) {
        int byte = (vdh0 + j) * 128 + vkey * 2;
        byte ^= (j << 4);                      // (dh&7)==j since vdh0%8==0
        *reinterpret_cast<u16*>(VsB + byte) = (u16)vvv[j];
      }
      __syncthreads();

      const bool active = (kv0 <= q0w + 15);   // wave-uniform; skip fully-masked diag tiles
      if (active) {
        // ---- QK^T ----
        f32x4 sc[4];
#pragma unroll
        for (int f = 0; f < 4; ++f) {
          int row = f * 16 + lq;
          s16x8 kb0 = *reinterpret_cast<const s16x8*>(KsB + row * 128 + ((g ^ (row & 7)) << 4));
          s16x8 kb1 = *reinterpret_cast<const s16x8*>(KsB + row * 128 + (((g + 4) ^ (row & 7)) << 4));
          f32x4 z = {0.f, 0.f, 0.f, 0.f};
          z = __builtin_amdgcn_mfma_f32_16x16x32_bf16(qf0, kb0, z, 0, 0, 0);
          z = __builtin_amdgcn_mfma_f32_16x16x32_bf16(qf1, kb1, z, 0, 0, 0);
          sc[f] = z;
        }

        if (kv0 + 63 > q0w) {  // diagonal tile: causal mask
#pragma unroll
          for (int f = 0; f < 4; ++f)
#pragma unroll
            for (int r = 0; r < 4; ++r) {
              int key = kv0 + f * 16 + lq;
              int q = q0w + g * 4 + r;
              if (key > q) sc[f][r] = -1e30f;
            }
        }

        // ---- online softmax (q-rows spread across 16 lq lanes) ----
        float alpha[4];
#pragma unroll
        for (int r = 0; r < 4; ++r) {
          float v = fmaxf(fmaxf(sc[0][r], sc[1][r]), fmaxf(sc[2][r], sc[3][r]));
          v = fmaxf(v, __shfl_xor(v, 1));
          v = fmaxf(v, __shfl_xor(v, 2));
          v = fmaxf(v, __shfl_xor(v, 4));
          v = fmaxf(v, __shfl_xor(v, 8));
          float mn = fmaxf(m[r], v);
          alpha[r] = __expf(m[r] - mn);
          m[r] = mn;
        }
#pragma unroll
        for (int f = 0; f < 4; ++f)
#pragma unroll
          for (int r = 0; r < 4; ++r)
            sc[f][r] = __expf(sc[f][r] - m[r]);
#pragma unroll
        for (int r = 0; r < 4; ++r) {
          float s = sc[0][r] + sc[1][r] + sc[2][r] + sc[3][r];
          s += __shfl_xor(s, 1);
          s += __shfl_xor(s, 2);
          s += __shfl_xor(s, 4);
          s += __shfl_xor(s, 8);
          l[r] = l[r] * alpha[r] + s;
          o[0][r] *= alpha[r]; o[1][r] *= alpha[r];
          o[2][r] *= alpha[r]; o[3][r] *= alpha[r];
        }

        // ---- P layout-turn via per-wave LDS, then PV ----
#pragma unroll
        for (int f = 0; f < 4; ++f)
#pragma unroll
          for (int r = 0; r < 4; ++r)
            Ps[wid][(g * 4 + r) * PSTR + f * 16 + lq] = f2b(sc[f][r]);

        s16x8 pa0 = *reinterpret_cast<const s16x8*>(&Ps[wid][lq * PSTR + g * 8]);
        s16x8 pa1 = *reinterpret_cast<const s16x8*>(&Ps[wid][lq * PSTR + g * 8 + 32]);
#pragma unroll
        for (int ni = 0; ni < 4; ++ni) {
          int row = ni * 16 + lq;
          s16x8 vb0 = *reinterpret_cast<const s16x8*>(VsB + row * 128 + ((g ^ (row & 7)) << 4));
          s16x8 vb1 = *reinterpret_cast<const s16x8*>(VsB + row * 128 + (((g + 4) ^ (row & 7)) << 4));
          o[ni] = __builtin_amdgcn_mfma_f32_16x16x32_bf16(pa0, vb0, o[ni], 0, 0, 0);
          o[ni] = __builtin_amdgcn_mfma_f32_16x16x32_bf16(pa1, vb1, o[ni], 0, 0, 0);
        }
      }
      __syncthreads();
    }

    // ---- write out [B][S][H][DH] f32 ----
#pragma unroll
    for (int r = 0; r < 4; ++r) {
      float inv = 1.0f / l[r];
      int s = q0w + g * 4 + r;
      float* op = out + (((size_t)b * Sz + s) * Hz + h) * DHz;
#pragma unroll
      for (int ni = 0; ni < 4; ++ni)
        op[ni * 16 + lq] = o[ni][r] * inv;
    }
  }
}

extern "C" void kernel_launch(void* const* d_in, const int* in_sizes, int n_in,
                              void* d_out, int out_size, void* d_ws, size_t ws_size,
                              hipStream_t stream) {
  const float* x    = (const float*)d_in[0];
  const float* W    = (const float*)d_in[1];
  const float* bias = (const float*)d_in[2];
  float* out = (float*)d_out;

  char* ws = (char*)d_ws;
  u16* xb = (u16*)(ws);                      // 16 MB
  u16* wt = (u16*)(ws + 16777216);           // 6 MB
  u16* Qb = (u16*)(ws + 23068672);           // 16 MB
  u16* Kb = (u16*)(ws + 39845888);           // 16 MB
  u16* Vb = (u16*)(ws + 56623104);           // 16 MB  (total ~70 MB)

  cvt_x<<<8192, 256, 0, stream>>>(x, xb);
  transpose_w<<<dim3(96, 32), dim3(32, 8), 0, stream>>>(W, wt);
  qkv_gemm<<<dim3(Mz / BM, N3z / BN), 256, 0, stream>>>(xb, wt, bias, Qb, Kb, Vb);
  attn_kernel<<<dim3(8, Bz * Hz), 512, 0, stream>>>(Qb, Kb, Vb, out);
}

// Round 5
// 233.458 us; speedup vs baseline: 1.8429x; 1.1229x over previous
//
#include <hip/hip_runtime.h>
#include <hip/hip_bf16.h>

#define Bz 4
#define Sz 2048
#define Dz 1024
#define Hz 16
#define DHz 64
#define Mz (Bz*Sz)      // 8192
#define N3z (3*Dz)      // 3072
#define Kz Dz           // 1024

typedef short s16x8 __attribute__((ext_vector_type(8)));
typedef float f32x4 __attribute__((ext_vector_type(4)));
typedef unsigned short u16;

__device__ __forceinline__ u16 f2b(float f) {
  union { float f; unsigned u; } v; v.f = f;
  unsigned r = v.u + 0x7FFFu + ((v.u >> 16) & 1u);
  return (u16)(r >> 16);
}

__device__ __forceinline__ unsigned cvt_pk_bf16(float lo, float hi) {
  unsigned r;
  asm("v_cvt_pk_bf16_f32 %0, %1, %2" : "=v"(r) : "v"(lo), "v"(hi));
  return r;
}

// ---------------- x (f32) -> bf16, linear ----------------
__global__ __launch_bounds__(256) void cvt_x(const float* __restrict__ x,
                                             u16* __restrict__ xb) {
  int i = (blockIdx.x * 256 + threadIdx.x) * 4;
  float4 v = *reinterpret_cast<const float4*>(x + i);
  ushort4 o;
  o.x = f2b(v.x); o.y = f2b(v.y); o.z = f2b(v.z); o.w = f2b(v.w);
  *reinterpret_cast<ushort4*>(xb + i) = o;
}

// ---------------- W [K][3D] f32 -> Wt [3D][K] bf16 ----------------
__global__ __launch_bounds__(256) void transpose_w(const float* __restrict__ W,
                                                   u16* __restrict__ Wt) {
  __shared__ u16 t[32][33];
  int nb = blockIdx.x;
  int kb = blockIdx.y;
  int tx = threadIdx.x, ty = threadIdx.y;
#pragma unroll
  for (int j = 0; j < 4; ++j) {
    int k = kb * 32 + ty + j * 8;
    t[ty + j * 8][tx] = f2b(W[(size_t)k * N3z + nb * 32 + tx]);
  }
  __syncthreads();
#pragma unroll
  for (int j = 0; j < 4; ++j) {
    int n = nb * 32 + ty + j * 8;
    Wt[(size_t)n * Kz + kb * 32 + tx] = t[tx][ty + j * 8];
  }
}

// ---------------- QKV GEMM: [8192,1024] x [1024,3072] + bias ----------------
#define BM 128
#define BN 128
#define BKs 32
#define QSCALE (0.125f * 1.44269504088896f)   // 1/sqrt(64) * log2(e): exp2-domain

__global__ __launch_bounds__(256) void qkv_gemm(
    const u16* __restrict__ A, const u16* __restrict__ Bt,
    const float* __restrict__ bias,
    u16* __restrict__ Qo, u16* __restrict__ Ko, u16* __restrict__ Vo) {
  __shared__ alignas(16) u16 As[BM * BKs];
  __shared__ alignas(16) u16 Bs[BN * BKs];
  const int tid = threadIdx.x;
  const int wid = tid >> 6, lane = tid & 63;
  const int wr = wid >> 1, wc = wid & 1;
  const int g = lane >> 4, lq = lane & 15;
  const int brow = blockIdx.x * BM;
  const int bcol = blockIdx.y * BN;

  f32x4 acc[4][4] = {};

  for (int kt = 0; kt < Kz; kt += BKs) {
#pragma unroll
    for (int c = 0; c < 2; ++c) {
      int row = (wid * 2 + c) * 16 + (lane >> 2);
      int off = (lane & 3) * 8;
      const u16* ga = A + (size_t)(brow + row) * Kz + kt + off;
      __builtin_amdgcn_global_load_lds(
          (const __attribute__((address_space(1))) void*)ga,
          (__attribute__((address_space(3))) void*)&As[(wid * 2 + c) * 512],
          16, 0, 0);
      const u16* gb = Bt + (size_t)(bcol + row) * Kz + kt + off;
      __builtin_amdgcn_global_load_lds(
          (const __attribute__((address_space(1))) void*)gb,
          (__attribute__((address_space(3))) void*)&Bs[(wid * 2 + c) * 512],
          16, 0, 0);
    }
    __syncthreads();

    s16x8 af[4], bfr[4];
#pragma unroll
    for (int i = 0; i < 4; ++i) {
      af[i]  = *reinterpret_cast<const s16x8*>(&As[(wr * 64 + i * 16 + lq) * BKs + g * 8]);
      bfr[i] = *reinterpret_cast<const s16x8*>(&Bs[(wc * 64 + i * 16 + lq) * BKs + g * 8]);
    }
#pragma unroll
    for (int mi = 0; mi < 4; ++mi)
#pragma unroll
      for (int ni = 0; ni < 4; ++ni)
        acc[mi][ni] = __builtin_amdgcn_mfma_f32_16x16x32_bf16(af[mi], bfr[ni], acc[mi][ni], 0, 0, 0);
    __syncthreads();
  }

#pragma unroll
  for (int ni = 0; ni < 4; ++ni) {
    int gcol = bcol + wc * 64 + ni * 16 + lq;
    int h = gcol / 192;
    int rem = gcol - h * 192;
    int tt = rem >> 6;
    int dh = rem & 63;
    float bv = bias[gcol];
    u16* dst = (tt == 0) ? Qo : (tt == 1) ? Ko : Vo;
    float scale = (tt == 0) ? QSCALE : 1.0f;
#pragma unroll
    for (int mi = 0; mi < 4; ++mi) {
#pragma unroll
      for (int r = 0; r < 4; ++r) {
        int grow = brow + wr * 64 + mi * 16 + g * 4 + r;
        int bb = grow >> 11;
        int ss = grow & 2047;
        float v = (acc[mi][ni][r] + bv) * scale;
        dst[(((size_t)bb * Hz + h) * Sz + ss) * DHz + dh] = f2b(v);
      }
    }
  }
}

// ---------------- causal flash attention ----------------
// grid (8 qpairs, 64 bh), 512 thr = 8 waves; block does q-tiles qp and 15-qp
// (128 rows each) -> uniform 34 K-tiles (perfect causal balance).
// Swapped QK^T (mfma(K,Q)): lane holds P-row q=lq spread over g-groups ->
// in-register softmax; P->A-frag via cvt_pk + 8 paired shfls with
// source-parity publish (dest classes cb=g>>1 are disjoint per parity).
// exp2 domain (Q pre-scaled by log2e/8). T13 defer-max THR=8.
// K and V^T in LDS [64][64] with XOR swizzle byte^=((row&7)<<4) both sides.
__global__ __launch_bounds__(512, 4) void attn_kernel(
    const u16* __restrict__ Qg, const u16* __restrict__ Kg,
    const u16* __restrict__ Vg, float* __restrict__ out) {
  __shared__ alignas(16) u16 Ks[64 * 64];         // 8192 B, swizzled
  __shared__ alignas(16) u16 Vs[64 * 64];         // 8192 B, V^T [dh][key], swizzled

  const int qpair = blockIdx.x;
  const int bh = blockIdx.y;
  const int tid = threadIdx.x;
  const int wid = tid >> 6, lane = tid & 63;
  const int g = lane >> 4, lq = lane & 15;
  const size_t base = (size_t)bh * Sz * DHz;
  const int b = bh >> 4, h = bh & 15;

  const int krow = tid >> 3;
  const int kslot = tid & 7;
  const int kswz = kslot ^ (krow & 7);
  const int vkey = tid & 63;
  const int vdh0 = (tid >> 6) * 8;

  char* KsB = (char*)Ks;
  char* VsB = (char*)Vs;

  // P-redistribution geometry:
  //   source lanes for this dest: sA (g'=2(g&1), parity 0), sB (g'=2(g&1)+1, parity 1)
  //   dest class cb = g>>1 selects w[cb]/w[2+cb]; even shfls publish
  //   (p ? w[1+..] : w[0+..]), odd shfls the swap -> conflict-free.
  const int p = g & 1;          // publish parity (this lane as SOURCE)
  const int cb = g >> 1;        // class bit (this lane as DEST)
  const int sA = 32 * (g & 1) + lq;
  const int sB = sA + 16;
  const int sEven = cb ? sB : sA;
  const int sOdd  = cb ? sA : sB;

  for (int half = 0; half < 2; ++half) {
    const int qt = half ? (15 - qpair) : qpair;
    const int q0w = qt * 128 + wid * 16;
    const int qrow = q0w + lq;                     // this lane's softmax q-row

    s16x8 qf0 = *reinterpret_cast<const s16x8*>(Qg + base + (size_t)(q0w + lq) * DHz + g * 8);
    s16x8 qf1 = *reinterpret_cast<const s16x8*>(Qg + base + (size_t)(q0w + lq) * DHz + g * 8 + 32);

    f32x4 o[4] = {};
    float m1 = -1e30f;
    float l1 = 0.f;

    const int nt = 2 * qt + 2;
    for (int t = 0; t < nt; ++t) {
      const int kv0 = t * 64;

      // ---- stage K [key][dh] swizzled ----
      s16x8 kvv = *reinterpret_cast<const s16x8*>(Kg + base + (size_t)(kv0 + krow) * DHz + kslot * 8);
      *reinterpret_cast<s16x8*>(KsB + krow * 128 + kswz * 16) = kvv;
      // ---- stage V^T [dh][key] swizzled ----
      s16x8 vvv = *reinterpret_cast<const s16x8*>(Vg + base + (size_t)(kv0 + vkey) * DHz + vdh0);
#pragma unroll
      for (int j = 0; j < 8; ++j) {
        int byte = (vdh0 + j) * 128 + vkey * 2;
        byte ^= (j << 4);
        *reinterpret_cast<u16*>(VsB + byte) = (u16)vvv[j];
      }
      __syncthreads();

      const bool active = (kv0 <= q0w + 15);
      if (active) {
        // ---- swapped QK^T: z[f][r] = S[q=lq][key=kv0+f*16+g*4+r] ----
        f32x4 z[4];
#pragma unroll
        for (int f = 0; f < 4; ++f) {
          int row = f * 16 + lq;
          s16x8 kb0 = *reinterpret_cast<const s16x8*>(KsB + row * 128 + ((g ^ (row & 7)) << 4));
          s16x8 kb1 = *reinterpret_cast<const s16x8*>(KsB + row * 128 + (((g + 4) ^ (row & 7)) << 4));
          f32x4 zz = {0.f, 0.f, 0.f, 0.f};
          zz = __builtin_amdgcn_mfma_f32_16x16x32_bf16(kb0, qf0, zz, 0, 0, 0);
          zz = __builtin_amdgcn_mfma_f32_16x16x32_bf16(kb1, qf1, zz, 0, 0, 0);
          z[f] = zz;
        }

        if (kv0 + 63 > q0w) {  // diagonal tile: causal mask (key > q)
#pragma unroll
          for (int f = 0; f < 4; ++f)
#pragma unroll
            for (int r = 0; r < 4; ++r) {
              int key = kv0 + f * 16 + g * 4 + r;
              if (key > qrow) z[f][r] = -1e30f;
            }
        }

        // ---- row max: in-lane 16 + reduce across g-groups ----
        float pm = z[0][0];
#pragma unroll
        for (int f = 0; f < 4; ++f)
#pragma unroll
          for (int r = 0; r < 4; ++r) pm = fmaxf(pm, z[f][r]);
        pm = fmaxf(pm, __shfl_xor(pm, 16));
        pm = fmaxf(pm, __shfl_xor(pm, 32));

        // ---- T13 defer-max ----
        if (!__all(pm <= m1 + 8.0f)) {
          float mn = fmaxf(m1, pm);
          float a = exp2f(m1 - mn);
          m1 = mn;
          l1 *= a;
          float a0 = __shfl(a, 4 * g + 0);
          float a1 = __shfl(a, 4 * g + 1);
          float a2 = __shfl(a, 4 * g + 2);
          float a3 = __shfl(a, 4 * g + 3);
#pragma unroll
          for (int ni = 0; ni < 4; ++ni) {
            o[ni][0] *= a0; o[ni][1] *= a1; o[ni][2] *= a2; o[ni][3] *= a3;
          }
        }

        // ---- p = exp2(z - m), sum, pack to bf16 pairs ----
        float s = 0.f;
        unsigned w[4][2];
#pragma unroll
        for (int f = 0; f < 4; ++f) {
          float p0 = exp2f(z[f][0] - m1);
          float p1 = exp2f(z[f][1] - m1);
          float p2 = exp2f(z[f][2] - m1);
          float p3 = exp2f(z[f][3] - m1);
          s += (p0 + p1) + (p2 + p3);
          w[f][0] = cvt_pk_bf16(p0, p1);
          w[f][1] = cvt_pk_bf16(p2, p3);
        }
        s += __shfl_xor(s, 16);
        s += __shfl_xor(s, 32);
        l1 += s;

        // ---- redistribute P into PV A-fragments: 8 paired shfls ----
        // dest lane (g,lq) needs A0 = P[lq][g*8..g*8+7], A1 = +32.
        int e0 = __shfl((int)(p ? w[1][0] : w[0][0]), sEven);
        int o0 = __shfl((int)(p ? w[0][0] : w[1][0]), sOdd);
        int e1 = __shfl((int)(p ? w[1][1] : w[0][1]), sEven);
        int o1 = __shfl((int)(p ? w[0][1] : w[1][1]), sOdd);
        int e2 = __shfl((int)(p ? w[3][0] : w[2][0]), sEven);
        int o2 = __shfl((int)(p ? w[2][0] : w[3][0]), sOdd);
        int e3 = __shfl((int)(p ? w[3][1] : w[2][1]), sEven);
        int o3 = __shfl((int)(p ? w[2][1] : w[3][1]), sOdd);
        union { int i[4]; s16x8 v; } A0, A1;
        A0.i[0] = cb ? o0 : e0;
        A0.i[2] = cb ? e0 : o0;
        A0.i[1] = cb ? o1 : e1;
        A0.i[3] = cb ? e1 : o1;
        A1.i[0] = cb ? o2 : e2;
        A1.i[2] = cb ? e2 : o2;
        A1.i[1] = cb ? o3 : e3;
        A1.i[3] = cb ? e3 : o3;

        // ---- PV ----
#pragma unroll
        for (int ni = 0; ni < 4; ++ni) {
          int row = ni * 16 + lq;
          s16x8 vb0 = *reinterpret_cast<const s16x8*>(VsB + row * 128 + ((g ^ (row & 7)) << 4));
          s16x8 vb1 = *reinterpret_cast<const s16x8*>(VsB + row * 128 + (((g + 4) ^ (row & 7)) << 4));
          o[ni] = __builtin_amdgcn_mfma_f32_16x16x32_bf16(A0.v, vb0, o[ni], 0, 0, 0);
          o[ni] = __builtin_amdgcn_mfma_f32_16x16x32_bf16(A1.v, vb1, o[ni], 0, 0, 0);
        }
      }
      __syncthreads();
    }

    // ---- write out [B][S][H][DH] f32; l lives on row lq -> shfl to o-rows ----
    float lr0 = __shfl(l1, 4 * g + 0);
    float lr1 = __shfl(l1, 4 * g + 1);
    float lr2 = __shfl(l1, 4 * g + 2);
    float lr3 = __shfl(l1, 4 * g + 3);
    float inv[4] = {1.0f / lr0, 1.0f / lr1, 1.0f / lr2, 1.0f / lr3};
#pragma unroll
    for (int r = 0; r < 4; ++r) {
      int s = q0w + g * 4 + r;
      float* op = out + (((size_t)b * Sz + s) * Hz + h) * DHz;
#pragma unroll
      for (int ni = 0; ni < 4; ++ni)
        op[ni * 16 + lq] = o[ni][r] * inv[r];
    }
  }
}

extern "C" void kernel_launch(void* const* d_in, const int* in_sizes, int n_in,
                              void* d_out, int out_size, void* d_ws, size_t ws_size,
                              hipStream_t stream) {
  const float* x    = (const float*)d_in[0];
  const float* W    = (const float*)d_in[1];
  const float* bias = (const float*)d_in[2];
  float* out = (float*)d_out;

  char* ws = (char*)d_ws;
  u16* xb = (u16*)(ws);                      // 16 MB
  u16* wt = (u16*)(ws + 16777216);           // 6 MB
  u16* Qb = (u16*)(ws + 23068672);           // 16 MB
  u16* Kb = (u16*)(ws + 39845888);           // 16 MB
  u16* Vb = (u16*)(ws + 56623104);           // 16 MB

  cvt_x<<<8192, 256, 0, stream>>>(x, xb);
  transpose_w<<<dim3(96, 32), dim3(32, 8), 0, stream>>>(W, wt);
  qkv_gemm<<<dim3(Mz / BM, N3z / BN), 256, 0, stream>>>(xb, wt, bias, Qb, Kb, Vb);
  attn_kernel<<<dim3(8, Bz * Hz), 512, 0, stream>>>(Qb, Kb, Vb, out);
}